// Round 1
// baseline (559.705 us; speedup 1.0000x reference)
//
#include <hip/hip_runtime.h>
#include <hip/hip_bf16.h>

typedef __bf16 bf16;
typedef __bf16 bf16x4 __attribute__((ext_vector_type(4)));
typedef __bf16 bf16x8 __attribute__((ext_vector_type(8)));
typedef float  f32x4  __attribute__((ext_vector_type(4)));

#define H_DIM 1024
#define NHEAD 16
#define HD    64

// ---------------- weight fp32 [K][N] -> bf16 [N][K] (transpose+convert) ----------------
__global__ __launch_bounds__(256) void wconv_kernel(const float* __restrict__ W,
                                                    bf16* __restrict__ Wt,
                                                    int K, int N) {
    __shared__ float tile[64][65];
    const int n0 = blockIdx.x * 64, k0 = blockIdx.y * 64;
    const int t = threadIdx.x;
#pragma unroll
    for (int p = 0; p < 4; ++p) {
        int lin = p * 1024 + t * 4;
        int r = lin >> 6, c = lin & 63;
        f32x4 v = *(const f32x4*)(W + (size_t)(k0 + r) * N + n0 + c);
        tile[r][c]     = v[0];
        tile[r][c + 1] = v[1];
        tile[r][c + 2] = v[2];
        tile[r][c + 3] = v[3];
    }
    __syncthreads();
#pragma unroll
    for (int p = 0; p < 4; ++p) {
        int lin = p * 1024 + t * 4;
        int rn = lin >> 6, ck = lin & 63;
        bf16x4 o;
#pragma unroll
        for (int j = 0; j < 4; ++j) o[j] = (bf16)tile[ck + j][rn];
        *(bf16x4*)(Wt + (size_t)(n0 + rn) * K + k0 + ck) = o;
    }
}

// ---------------- layernorm (fp32 in, bf16 out), one row per block ----------------
__global__ __launch_bounds__(256) void ln_kernel(const float* __restrict__ in, float inScale,
                                                 const float* __restrict__ g,
                                                 const float* __restrict__ b,
                                                 bf16* __restrict__ out) {
    const int row = blockIdx.x, t = threadIdx.x;
    const float* p = in + (size_t)row * H_DIM;
    f32x4 v = *(const f32x4*)(p + t * 4);
    v *= inScale;
    float s1 = v[0] + v[1] + v[2] + v[3];
    float s2 = v[0] * v[0] + v[1] * v[1] + v[2] * v[2] + v[3] * v[3];
#pragma unroll
    for (int m = 1; m < 64; m <<= 1) {
        s1 += __shfl_xor(s1, m);
        s2 += __shfl_xor(s2, m);
    }
    __shared__ float red[8];
    const int wave = t >> 6;
    if ((t & 63) == 0) { red[wave * 2] = s1; red[wave * 2 + 1] = s2; }
    __syncthreads();
    s1 = red[0] + red[2] + red[4] + red[6];
    s2 = red[1] + red[3] + red[5] + red[7];
    float mean = s1 * (1.0f / H_DIM);
    float var  = s2 * (1.0f / H_DIM) - mean * mean;
    float inv  = rsqrtf(var + 1e-5f);
    f32x4 gg = *(const f32x4*)(g + t * 4);
    f32x4 bb = *(const f32x4*)(b + t * 4);
    bf16x4 o;
#pragma unroll
    for (int j = 0; j < 4; ++j) o[j] = (bf16)((v[j] - mean) * inv * gg[j] + bb[j]);
    *(bf16x4*)(out + (size_t)row * H_DIM + t * 4) = o;
}

// ---------------- fp32 -> bf16 with scale ----------------
__global__ __launch_bounds__(256) void cvt_scale_kernel(const float* __restrict__ in,
                                                        bf16* __restrict__ out,
                                                        float s, int n4) {
    int i = blockIdx.x * 256 + threadIdx.x;
    if (i < n4) {
        f32x4 v = *(const f32x4*)(in + (size_t)i * 4);
        bf16x4 o;
#pragma unroll
        for (int j = 0; j < 4; ++j) o[j] = (bf16)(v[j] * s);
        *(bf16x4*)(out + (size_t)i * 4) = o;
    }
}

// ---------------- GEMM: C[M,N] = A[M,K](bf16) * Bt[N,K]^T(bf16) + bias, fused epilogues ----------------
template <bool OUT_BF16, bool GELU_EPI, bool HAS_RES>
__global__ __launch_bounds__(256) void gemm_kernel(const bf16* __restrict__ A,
                                                   const bf16* __restrict__ Bt,
                                                   const float* __restrict__ bias,
                                                   const float* __restrict__ res,
                                                   void* __restrict__ outp,
                                                   int M, int N, int K,
                                                   float resScale, float outScale) {
    __shared__ bf16 Al[128][72];   // +8 elem (16B) row pad: 2-way bank aliasing only
    __shared__ bf16 Bl[128][72];
    const int m0 = blockIdx.y * 128, n0 = blockIdx.x * 128;
    const int tid = threadIdx.x;
    const int wave = tid >> 6, lane = tid & 63, lr = lane & 15, lhi = lane >> 4;
    const int wr = wave >> 1, wc = wave & 1;
    f32x4 acc[4][4] = {};
    for (int k0 = 0; k0 < K; k0 += 64) {
        __syncthreads();
#pragma unroll
        for (int p = 0; p < 4; ++p) {
            int lin = (p * 256 + tid) * 8;
            int r = lin >> 6, c = lin & 63;
            *(bf16x8*)&Al[r][c] = *(const bf16x8*)(A + (size_t)(m0 + r) * K + k0 + c);
            *(bf16x8*)&Bl[r][c] = *(const bf16x8*)(Bt + (size_t)(n0 + r) * K + k0 + c);
        }
        __syncthreads();
#pragma unroll
        for (int kk = 0; kk < 2; ++kk) {
            bf16x8 af[4], bfr[4];
#pragma unroll
            for (int i = 0; i < 4; ++i) {
                af[i]  = *(const bf16x8*)&Al[wr * 64 + i * 16 + lr][kk * 32 + lhi * 8];
                bfr[i] = *(const bf16x8*)&Bl[wc * 64 + i * 16 + lr][kk * 32 + lhi * 8];
            }
#pragma unroll
            for (int i = 0; i < 4; ++i)
#pragma unroll
                for (int j = 0; j < 4; ++j)
                    acc[i][j] = __builtin_amdgcn_mfma_f32_16x16x32_bf16(af[i], bfr[j], acc[i][j], 0, 0, 0);
        }
    }
#pragma unroll
    for (int i = 0; i < 4; ++i) {
#pragma unroll
        for (int j = 0; j < 4; ++j) {
            const int col = n0 + wc * 64 + j * 16 + lr;
            const float bv = bias[col];
#pragma unroll
            for (int r = 0; r < 4; ++r) {
                const int row = m0 + wr * 64 + i * 16 + lhi * 4 + r;
                const size_t idx = (size_t)row * N + col;
                float v = acc[i][j][r] + bv;
                if (HAS_RES) v += res[idx] * resScale;
                if (GELU_EPI) v = 0.5f * v * (1.0f + erff(v * 0.70710678118654752f));
                v *= outScale;
                if (OUT_BF16) ((bf16*)outp)[idx] = (bf16)v;
                else          ((float*)outp)[idx] = v;
            }
        }
    }
}

// ---------------- flash attention: 64 q-rows/block, KV tiles of 64 ----------------
__global__ __launch_bounds__(256) void attn_kernel(const bf16* __restrict__ Qb,
                                                   const bf16* __restrict__ Kb,
                                                   const bf16* __restrict__ Vb,
                                                   bf16* __restrict__ Ob,
                                                   int SQ, int SK, float scale) {
    __shared__ bf16 Kl[64][72];
    __shared__ bf16 Vt[64][72];       // V transposed: Vt[d][key]
    __shared__ bf16 Pl[4][16][72];    // per-wave P relayout buffer
    const int b = blockIdx.x >> 4, h = blockIdx.x & 15;
    const int q0 = blockIdx.y * 64;
    const int tid = threadIdx.x, wave = tid >> 6, lane = tid & 63;
    const int lr = lane & 15, lhi = lane >> 4;

    const bf16* qp = Qb + ((size_t)(b * SQ) + q0 + wave * 16 + lr) * H_DIM + h * HD;
    bf16x8 qf0 = *(const bf16x8*)(qp + lhi * 8);
    bf16x8 qf1 = *(const bf16x8*)(qp + 32 + lhi * 8);

    float mrun[4], lrun[4];
    f32x4 o[4] = {};
#pragma unroll
    for (int r = 0; r < 4; ++r) { mrun[r] = -1e30f; lrun[r] = 0.f; }

    for (int kb = 0; kb < SK; kb += 64) {
        __syncthreads();
#pragma unroll
        for (int p = 0; p < 2; ++p) {
            int lin = (p * 256 + tid) * 8;
            int r = lin >> 6, c = lin & 63;
            const size_t gro = ((size_t)(b * SK) + kb + r) * H_DIM + h * HD + c;
            *(bf16x8*)&Kl[r][c] = *(const bf16x8*)(Kb + gro);
            bf16x8 vv = *(const bf16x8*)(Vb + gro);
#pragma unroll
            for (int j = 0; j < 8; ++j) Vt[c + j][r] = vv[j];
        }
        __syncthreads();

        // scores: S[16q x 64k] per wave
        f32x4 s[4];
#pragma unroll
        for (int nf = 0; nf < 4; ++nf) {
            f32x4 sc = {};
            bf16x8 kf0 = *(const bf16x8*)&Kl[nf * 16 + lr][lhi * 8];
            bf16x8 kf1 = *(const bf16x8*)&Kl[nf * 16 + lr][32 + lhi * 8];
            sc = __builtin_amdgcn_mfma_f32_16x16x32_bf16(qf0, kf0, sc, 0, 0, 0);
            sc = __builtin_amdgcn_mfma_f32_16x16x32_bf16(qf1, kf1, sc, 0, 0, 0);
            s[nf] = sc * scale;
        }
        // online softmax (row stats across lanes lr, rows indexed by lhi*4+r)
        float tm[4];
#pragma unroll
        for (int r = 0; r < 4; ++r)
            tm[r] = fmaxf(fmaxf(s[0][r], s[1][r]), fmaxf(s[2][r], s[3][r]));
#pragma unroll
        for (int m = 1; m < 16; m <<= 1)
#pragma unroll
            for (int r = 0; r < 4; ++r) tm[r] = fmaxf(tm[r], __shfl_xor(tm[r], m));
        float alpha[4];
#pragma unroll
        for (int r = 0; r < 4; ++r) {
            float mn = fmaxf(mrun[r], tm[r]);
            alpha[r] = __expf(mrun[r] - mn);
            mrun[r] = mn;
        }
        float rs[4] = {0.f, 0.f, 0.f, 0.f};
#pragma unroll
        for (int nf = 0; nf < 4; ++nf)
#pragma unroll
            for (int r = 0; r < 4; ++r) {
                float pv = __expf(s[nf][r] - mrun[r]);
                s[nf][r] = pv;
                rs[r] += pv;
            }
#pragma unroll
        for (int m = 1; m < 16; m <<= 1)
#pragma unroll
            for (int r = 0; r < 4; ++r) rs[r] += __shfl_xor(rs[r], m);
#pragma unroll
        for (int r = 0; r < 4; ++r) lrun[r] = lrun[r] * alpha[r] + rs[r];
#pragma unroll
        for (int df = 0; df < 4; ++df)
#pragma unroll
            for (int r = 0; r < 4; ++r) o[df][r] *= alpha[r];
        // P relayout to MFMA-A layout via LDS
#pragma unroll
        for (int nf = 0; nf < 4; ++nf)
#pragma unroll
            for (int r = 0; r < 4; ++r)
                Pl[wave][lhi * 4 + r][nf * 16 + lr] = (bf16)s[nf][r];
        __syncthreads();
        // PV
#pragma unroll
        for (int kk = 0; kk < 2; ++kk) {
            bf16x8 pf = *(const bf16x8*)&Pl[wave][lr][kk * 32 + lhi * 8];
#pragma unroll
            for (int df = 0; df < 4; ++df) {
                bf16x8 vf = *(const bf16x8*)&Vt[df * 16 + lr][kk * 32 + lhi * 8];
                o[df] = __builtin_amdgcn_mfma_f32_16x16x32_bf16(pf, vf, o[df], 0, 0, 0);
            }
        }
    }
#pragma unroll
    for (int df = 0; df < 4; ++df)
#pragma unroll
        for (int r = 0; r < 4; ++r) {
            const int qrow = q0 + wave * 16 + lhi * 4 + r;
            Ob[((size_t)(b * SQ) + qrow) * H_DIM + h * HD + df * 16 + lr] =
                (bf16)(o[df][r] / lrun[r]);
        }
}

extern "C" void kernel_launch(void* const* d_in, const int* in_sizes, int n_in,
                              void* d_out, int out_size, void* d_ws, size_t ws_size,
                              hipStream_t stream) {
    const float* x    = (const float*)d_in[0];
    const float* img  = (const float*)d_in[1];
    const float* W_sq = (const float*)d_in[2];   const float* b_sq = (const float*)d_in[3];
    const float* W_sk = (const float*)d_in[4];   const float* b_sk = (const float*)d_in[5];
    const float* W_sv = (const float*)d_in[6];   const float* b_sv = (const float*)d_in[7];
    const float* W_so = (const float*)d_in[8];   const float* b_so = (const float*)d_in[9];
    const float* W_cq = (const float*)d_in[10];  const float* b_cq = (const float*)d_in[11];
    const float* W_ck = (const float*)d_in[12];  const float* b_ck = (const float*)d_in[13];
    const float* W_cv = (const float*)d_in[14];  const float* b_cv = (const float*)d_in[15];
    const float* W_co = (const float*)d_in[16];  const float* b_co = (const float*)d_in[17];
    const float* W_f1 = (const float*)d_in[18];  const float* b_f1 = (const float*)d_in[19];
    const float* W_f2 = (const float*)d_in[20];  const float* b_f2 = (const float*)d_in[21];
    const float* g1 = (const float*)d_in[22];    const float* bb1 = (const float*)d_in[23];
    const float* g2 = (const float*)d_in[24];    const float* bb2 = (const float*)d_in[25];
    const float* g3 = (const float*)d_in[26];    const float* bb3 = (const float*)d_in[27];

    char* ws = (char*)d_ws;
    const size_t MB = 1ull << 20;
    bf16* WT   = (bf16*)ws;                 // 16M bf16 elements = 32 MB
    bf16* w_sq = WT + 0 * (1u << 20);
    bf16* w_sk = WT + 1 * (1u << 20);
    bf16* w_sv = WT + 2 * (1u << 20);
    bf16* w_so = WT + 3 * (1u << 20);
    bf16* w_cq = WT + 4 * (1u << 20);
    bf16* w_ck = WT + 5 * (1u << 20);
    bf16* w_cv = WT + 6 * (1u << 20);
    bf16* w_co = WT + 7 * (1u << 20);
    bf16* w_f1 = WT + 8 * (1u << 20);       // [4096][1024]
    bf16* w_f2 = WT + 12 * (1u << 20);      // [1024][4096]
    float* XR  = (float*)(ws + 32 * MB);    // residual spine fp32 [4096,1024]
    bf16* NX   = (bf16*)(ws + 48 * MB);     // ln-out / attn-out bf16
    bf16* Qb   = (bf16*)(ws + 56 * MB);
    bf16* Kb   = (bf16*)(ws + 64 * MB);
    bf16* Vb   = (bf16*)(ws + 72 * MB);
    bf16* FF   = (bf16*)(ws + 56 * MB);     // reuse Q/K/V region: [4096,4096] bf16
    bf16* IMGB = (bf16*)(ws + 88 * MB);     // [512,1024] bf16

    const dim3 blk(256);

    // weight convert+transpose
    wconv_kernel<<<dim3(16, 16), blk, 0, stream>>>(W_sq, w_sq, 1024, 1024);
    wconv_kernel<<<dim3(16, 16), blk, 0, stream>>>(W_sk, w_sk, 1024, 1024);
    wconv_kernel<<<dim3(16, 16), blk, 0, stream>>>(W_sv, w_sv, 1024, 1024);
    wconv_kernel<<<dim3(16, 16), blk, 0, stream>>>(W_so, w_so, 1024, 1024);
    wconv_kernel<<<dim3(16, 16), blk, 0, stream>>>(W_cq, w_cq, 1024, 1024);
    wconv_kernel<<<dim3(16, 16), blk, 0, stream>>>(W_ck, w_ck, 1024, 1024);
    wconv_kernel<<<dim3(16, 16), blk, 0, stream>>>(W_cv, w_cv, 1024, 1024);
    wconv_kernel<<<dim3(16, 16), blk, 0, stream>>>(W_co, w_co, 1024, 1024);
    wconv_kernel<<<dim3(64, 16), blk, 0, stream>>>(W_f1, w_f1, 1024, 4096);
    wconv_kernel<<<dim3(16, 64), blk, 0, stream>>>(W_f2, w_f2, 4096, 1024);

    // ---- self attention ----
    ln_kernel<<<4096, blk, 0, stream>>>(x, 0.1f, g1, bb1, NX);
    gemm_kernel<true, false, false><<<dim3(8, 32), blk, 0, stream>>>(NX, w_sq, b_sq, nullptr, Qb, 4096, 1024, 1024, 0.f, 1.f);
    gemm_kernel<true, false, false><<<dim3(8, 32), blk, 0, stream>>>(NX, w_sk, b_sk, nullptr, Kb, 4096, 1024, 1024, 0.f, 1.f);
    gemm_kernel<true, false, false><<<dim3(8, 32), blk, 0, stream>>>(NX, w_sv, b_sv, nullptr, Vb, 4096, 1024, 1024, 0.f, 1.f);
    attn_kernel<<<dim3(32, 32), blk, 0, stream>>>(Qb, Kb, Vb, NX, 2048, 2048, 0.125f);
    gemm_kernel<false, false, true><<<dim3(8, 32), blk, 0, stream>>>(NX, w_so, b_so, x, XR, 4096, 1024, 1024, 0.1f, 1.f);

    // ---- cross attention ----
    ln_kernel<<<4096, blk, 0, stream>>>(XR, 1.f, g2, bb2, NX);
    gemm_kernel<true, false, false><<<dim3(8, 32), blk, 0, stream>>>(NX, w_cq, b_cq, nullptr, Qb, 4096, 1024, 1024, 0.f, 1.f);
    cvt_scale_kernel<<<dim3(512), blk, 0, stream>>>(img, IMGB, 0.1f, 131072);
    gemm_kernel<true, false, false><<<dim3(8, 4), blk, 0, stream>>>(IMGB, w_ck, b_ck, nullptr, Kb, 512, 1024, 1024, 0.f, 1.f);
    gemm_kernel<true, false, false><<<dim3(8, 4), blk, 0, stream>>>(IMGB, w_cv, b_cv, nullptr, Vb, 512, 1024, 1024, 0.f, 1.f);
    attn_kernel<<<dim3(32, 32), blk, 0, stream>>>(Qb, Kb, Vb, NX, 2048, 256, 0.125f);
    gemm_kernel<false, false, true><<<dim3(8, 32), blk, 0, stream>>>(NX, w_co, b_co, XR, XR, 4096, 1024, 1024, 1.f, 1.f);

    // ---- feed forward ----
    ln_kernel<<<4096, blk, 0, stream>>>(XR, 1.f, g3, bb3, NX);
    gemm_kernel<true, true, false><<<dim3(32, 32), blk, 0, stream>>>(NX, w_f1, b_f1, nullptr, FF, 4096, 4096, 1024, 0.f, 1.f);
    gemm_kernel<false, false, true><<<dim3(8, 32), blk, 0, stream>>>(FF, w_f2, b_f2, XR, d_out, 4096, 1024, 4096, 1.f, 10.f);
}